// Round 2
// baseline (381.928 us; speedup 1.0000x reference)
//
#include <hip/hip_runtime.h>
#include <hip/hip_bf16.h>

// Problem constants (fixed by setup_inputs)
#define NB   8      // batch
#define DK   256    // dk (4 mixtures x 64)
#define LL   2048   // Lq == Lk
#define DV   256    // dv
#define NMIX 4

typedef __attribute__((ext_vector_type(8))) short bf16x8;
typedef __attribute__((ext_vector_type(4))) float f32x4;

__device__ __forceinline__ unsigned short f2bf(float x) {
    unsigned int u = __float_as_uint(x);
    unsigned int r = (u + 0x7FFFu + ((u >> 16) & 1u)) >> 16;  // RNE
    return (unsigned short)r;
}
__device__ __forceinline__ float bf2f(unsigned short u) {
    return __uint_as_float(((unsigned int)u) << 16);
}

// ---------------------------------------------------------------------------
// (B, DK, LL) f32  ->  (B, LL, DK) bf16-bits   (used for both Q and K)
__global__ void transpose_cast_k(const float* __restrict__ in,
                                 unsigned short* __restrict__ out) {
    const int b  = blockIdx.z;
    const int ct = blockIdx.y;   // DK/32
    const int lt = blockIdx.x;   // LL/32
    __shared__ float tile[32][33];
    const int tx = threadIdx.x & 31;
    const int ty = threadIdx.x >> 5;   // 0..7
    const float* src = in + ((size_t)b * DK + ct * 32) * LL + lt * 32;
    #pragma unroll
    for (int r = 0; r < 4; ++r)
        tile[ty * 4 + r][tx] = src[(size_t)(ty * 4 + r) * LL + tx];
    __syncthreads();
    unsigned short* dst = out + ((size_t)b * LL + lt * 32) * DK + ct * 32;
    #pragma unroll
    for (int r = 0; r < 4; ++r)
        dst[(size_t)(ty * 4 + r) * DK + tx] = f2bf(tile[tx][ty * 4 + r]);
}

// elementwise cast (B*DV*LL) f32 -> bf16 bits (V keeps (dv, Lk) layout)
__global__ void cast_bf16_k(const float* __restrict__ in,
                            unsigned short* __restrict__ out) {
    size_t i = ((size_t)blockIdx.x * 256 + threadIdx.x) * 4;
    float4 v = *reinterpret_cast<const float4*>(in + i);
    ushort4 o;
    o.x = f2bf(v.x); o.y = f2bf(v.y); o.z = f2bf(v.z); o.w = f2bf(v.w);
    *reinterpret_cast<ushort4*>(out + i) = o;
}

// avg_query: one block per (b*DK + d) row, mean over LL
__global__ void avg_k(const float* __restrict__ q, float* __restrict__ avg) {
    const int row = blockIdx.x;
    const float* p = q + (size_t)row * LL;
    float s = 0.f;
    for (int i = threadIdx.x; i < LL; i += 256) s += p[i];
    #pragma unroll
    for (int off = 32; off >= 1; off >>= 1) s += __shfl_down(s, off);
    __shared__ float ps[4];
    if ((threadIdx.x & 63) == 0) ps[threadIdx.x >> 6] = s;
    __syncthreads();
    if (threadIdx.x == 0)
        avg[row] = (ps[0] + ps[1] + ps[2] + ps[3]) * (1.0f / LL);
}

// pi = softmax_m( w[m,:] . avg[b,:] ) ; one wave per b
__global__ void pi_k(const float* __restrict__ wgt, const float* __restrict__ avg,
                     float* __restrict__ piOut) {
    const int b = blockIdx.x;
    const int l = threadIdx.x;   // 0..63
    float part[NMIX] = {0.f, 0.f, 0.f, 0.f};
    for (int d = l; d < DK; d += 64) {
        float a = avg[b * DK + d];
        #pragma unroll
        for (int m = 0; m < NMIX; ++m) part[m] += wgt[m * DK + d] * a;
    }
    #pragma unroll
    for (int off = 1; off < 64; off <<= 1) {
        #pragma unroll
        for (int m = 0; m < NMIX; ++m) part[m] += __shfl_xor(part[m], off);
    }
    float mx = fmaxf(fmaxf(part[0], part[1]), fmaxf(part[2], part[3]));
    float e0 = __expf(part[0] - mx), e1 = __expf(part[1] - mx);
    float e2 = __expf(part[2] - mx), e3 = __expf(part[3] - mx);
    float z = e0 + e1 + e2 + e3;
    float mine = (l == 0) ? e0 : (l == 1) ? e1 : (l == 2) ? e2 : e3;
    if (l < NMIX) piOut[b * NMIX + l] = mine / z;
}

// ---------------------------------------------------------------------------
// Main fused kernel, v2 (swapped-operand structure).
// Block = 16 q-rows, 4 waves; wave w owns k-rows {i*128 + w*32 .. +31}.
// Swapped QK^T: S' = mfma(K, Q) -> lane holds S'[k-in-regs][q = lane&15].
// Window row-permutation f(i) = (i>>2)*8 + (i&3) makes each lane's 8 packed
// E-values cover 8 CONSECUTIVE physical k (base+lg*8..+7), so:
//   - attn rows are lane-local -> 2 coalesced float4 stores, no transpose
//   - V loads are single 16B loads per MFMA
//   - combined-E bf16x8 is directly the PV B-operand (k-mapping identical
//     on A (=V) and B sides, so any within-K permutation cancels).
// Waves exchange E via a small double-buffered LDS (1 barrier/pair) so each
// wave accumulates only a v-quarter (oacc = 16 VGPRs, no O reduction).
__launch_bounds__(256, 4)
__global__ void mos_attn(const unsigned short* __restrict__ Qt,
                         const unsigned short* __restrict__ Kt,
                         const unsigned short* __restrict__ Vb,
                         const float* __restrict__ piAll,
                         float* __restrict__ out,
                         float* __restrict__ attn) {
    const int bid  = blockIdx.x;
    const int b    = bid >> 7;          // 128 q-tiles per batch
    const int qt   = bid & 127;
    const int qb   = qt * 16;
    const int tid  = threadIdx.x;
    const int w    = tid >> 6;          // 0..3 (k-split)
    const int lane = tid & 63;
    const int lg   = lane >> 4;         // 0..3
    const int lc   = lane & 15;         // q-column

    __shared__ float Zpart[4][NMIX][16];
    __shared__ __align__(16) unsigned short Elds[2][4][4][16][8];  // [buf][kchunk][lg][lc][8]

    float pim[NMIX];
    #pragma unroll
    for (int m = 0; m < NMIX; ++m) pim[m] = piAll[b * NMIX + m];

    // Hoist Q fragments (B-operand: B[c=lg*8+j][col=q=lc])
    const unsigned short* qrow = Qt + ((size_t)b * LL + qb + lc) * DK + lg * 8;
    bf16x8 qf[NMIX][2];
    #pragma unroll
    for (int m = 0; m < NMIX; ++m)
        #pragma unroll
        for (int ch = 0; ch < 2; ++ch)
            qf[m][ch] = *reinterpret_cast<const bf16x8*>(qrow + m * 64 + ch * 32);

    const unsigned short* kb0 = Kt + (size_t)b * LL * DK;
    const float ES = 0.09016844005555896f;   // log2(e)/16

    // ---- sweep 1: denominators Z[m][q] (barrier-free loop) ----
    float zs[NMIX] = {0.f, 0.f, 0.f, 0.f};
    for (int kt = 0; kt < 32; ++kt) {
        const unsigned short* krow = kb0 + ((size_t)(kt * 64 + w * 16 + lc)) * DK + lg * 8;
        #pragma unroll
        for (int m = 0; m < NMIX; ++m) {
            bf16x8 k0 = *reinterpret_cast<const bf16x8*>(krow + m * 64);
            bf16x8 k1 = *reinterpret_cast<const bf16x8*>(krow + m * 64 + 32);
            f32x4 s = {0.f, 0.f, 0.f, 0.f};
            s = __builtin_amdgcn_mfma_f32_16x16x32_bf16(k0, qf[m][0], s, 0, 0, 0);
            s = __builtin_amdgcn_mfma_f32_16x16x32_bf16(k1, qf[m][1], s, 0, 0, 0);
            zs[m] += __builtin_amdgcn_exp2f(s[0] * ES) + __builtin_amdgcn_exp2f(s[1] * ES)
                   + __builtin_amdgcn_exp2f(s[2] * ES) + __builtin_amdgcn_exp2f(s[3] * ES);
        }
    }
    #pragma unroll
    for (int m = 0; m < NMIX; ++m) {
        float v = zs[m];
        v += __shfl_xor(v, 16);
        v += __shfl_xor(v, 32);
        zs[m] = v;
    }
    if (lane < 16) {
        #pragma unroll
        for (int m = 0; m < NMIX; ++m) Zpart[w][m][lane] = zs[m];
    }
    __syncthreads();

    float scl[NMIX];
    #pragma unroll
    for (int m = 0; m < NMIX; ++m)
        scl[m] = pim[m] / (Zpart[0][m][lc] + Zpart[1][m][lc] + Zpart[2][m][lc] + Zpart[3][m][lc]);

    // ---- sweep 2: attn + PV ----
    f32x4 oacc[4];
    #pragma unroll
    for (int j = 0; j < 4; ++j) oacc[j] = (f32x4){0.f, 0.f, 0.f, 0.f};

    const unsigned short* vrow[4];
    #pragma unroll
    for (int j = 0; j < 4; ++j)
        vrow[j] = Vb + ((size_t)b * DV + w * 64 + j * 16 + lc) * LL + lg * 8;

    float* attnRow = attn + ((size_t)b * LL + qb + lc) * LL;
    const int rAoff = ((lc >> 2) << 3) + (lc & 3);   // window row permutation

    for (int i = 0; i < 16; ++i) {
        const int base = i * 128 + w * 32;           // this wave's 32 k-rows
        const unsigned short* ka = kb0 + (size_t)(base + rAoff) * DK + lg * 8;
        float avA[4] = {0.f, 0.f, 0.f, 0.f};
        float avB[4] = {0.f, 0.f, 0.f, 0.f};
        #pragma unroll
        for (int m = 0; m < NMIX; ++m) {
            bf16x8 a0 = *reinterpret_cast<const bf16x8*>(ka + m * 64);
            bf16x8 a1 = *reinterpret_cast<const bf16x8*>(ka + m * 64 + 32);
            f32x4 s = {0.f, 0.f, 0.f, 0.f};
            s = __builtin_amdgcn_mfma_f32_16x16x32_bf16(a0, qf[m][0], s, 0, 0, 0);
            s = __builtin_amdgcn_mfma_f32_16x16x32_bf16(a1, qf[m][1], s, 0, 0, 0);
            #pragma unroll
            for (int r = 0; r < 4; ++r) avA[r] += scl[m] * __builtin_amdgcn_exp2f(s[r] * ES);
            bf16x8 b0 = *reinterpret_cast<const bf16x8*>(ka + 4 * DK + m * 64);
            bf16x8 b1 = *reinterpret_cast<const bf16x8*>(ka + 4 * DK + m * 64 + 32);
            f32x4 t = {0.f, 0.f, 0.f, 0.f};
            t = __builtin_amdgcn_mfma_f32_16x16x32_bf16(b0, qf[m][0], t, 0, 0, 0);
            t = __builtin_amdgcn_mfma_f32_16x16x32_bf16(b1, qf[m][1], t, 0, 0, 0);
            #pragma unroll
            for (int r = 0; r < 4; ++r) avB[r] += scl[m] * __builtin_amdgcn_exp2f(t[r] * ES);
        }
        // pack: lane's 8 E-values cover phys k = base + lg*8 .. +7
        bf16x8 epk;
        #pragma unroll
        for (int r = 0; r < 4; ++r) {
            epk[r]     = (short)f2bf(avA[r]);
            epk[r + 4] = (short)f2bf(avB[r]);
        }
        *reinterpret_cast<bf16x8*>(&Elds[i & 1][w][lg][lc][0]) = epk;
        __syncthreads();

        // attn store (bf16-rounded, matches PV operand; 2x float4 per lane)
        {
            f32x4 fa, fb;
            #pragma unroll
            for (int r = 0; r < 4; ++r) {
                fa[r] = bf2f((unsigned short)epk[r]);
                fb[r] = bf2f((unsigned short)epk[r + 4]);
            }
            *reinterpret_cast<f32x4*>(attnRow + base + lg * 8)     = fa;
            *reinterpret_cast<f32x4*>(attnRow + base + lg * 8 + 4) = fb;
        }

        // PV: oacc[j] += V[v-quarter][k] * E[k][q], k over this pair's 128 rows
        const int vcol0 = i * 128;
        #pragma unroll
        for (int c = 0; c < 4; ++c) {
            bf16x8 bq = *reinterpret_cast<const bf16x8*>(&Elds[i & 1][c][lg][lc][0]);
            #pragma unroll
            for (int j = 0; j < 4; ++j) {
                bf16x8 vf = *reinterpret_cast<const bf16x8*>(vrow[j] + vcol0 + c * 32);
                oacc[j] = __builtin_amdgcn_mfma_f32_16x16x32_bf16(vf, bq, oacc[j], 0, 0, 0);
            }
        }
    }

    // out: rows qb+lc, cols w*64 + j*16 + lg*4 + r (coalesced float4)
    float* outRow = out + ((size_t)b * LL + qb + lc) * DV + w * 64 + lg * 4;
    #pragma unroll
    for (int j = 0; j < 4; ++j)
        *reinterpret_cast<f32x4*>(outRow + j * 16) = oacc[j];
}

// ---------------------------------------------------------------------------
extern "C" void kernel_launch(void* const* d_in, const int* in_sizes, int n_in,
                              void* d_out, int out_size, void* d_ws, size_t ws_size,
                              hipStream_t stream) {
    const float* query   = (const float*)d_in[0];   // (8, 256, 2048)
    const float* key     = (const float*)d_in[1];   // (8, 256, 2048)
    const float* value   = (const float*)d_in[2];   // (8, 256, 2048)
    const float* weights = (const float*)d_in[3];   // (4, 256)

    float* out  = (float*)d_out;                         // (8, 2048, 256)
    float* attn = out + (size_t)NB * LL * DV;            // (8, 2048, 2048)

    // workspace layout (~25.2 MB)
    char* ws = (char*)d_ws;
    float* avg = (float*)ws;                             // 8*256 f32
    float* pi  = (float*)(ws + 8192);                    // 8*4 f32
    unsigned short* Qt = (unsigned short*)(ws + 16384);  // (8,2048,256) bf16
    unsigned short* Kt = Qt + (size_t)NB * LL * DK;
    unsigned short* Vb = Kt + (size_t)NB * LL * DK;      // (8,256,2048) bf16

    transpose_cast_k<<<dim3(LL / 32, DK / 32, NB), 256, 0, stream>>>(query, Qt);
    transpose_cast_k<<<dim3(LL / 32, DK / 32, NB), 256, 0, stream>>>(key, Kt);
    cast_bf16_k<<<(NB * DV * LL) / 1024, 256, 0, stream>>>(value, Vb);
    avg_k<<<NB * DK, 256, 0, stream>>>(query, avg);
    pi_k<<<NB, 64, 0, stream>>>(weights, avg, pi);
    mos_attn<<<NB * (LL / 16), 256, 0, stream>>>(Qt, Kt, Vb, pi, out, attn);
}

// Round 4
// 133.086 us; speedup vs baseline: 2.8698x; 2.8698x over previous
//
#include <hip/hip_runtime.h>
#include <hip/hip_bf16.h>

// Problem constants (fixed by setup_inputs)
#define NB   8      // batch
#define DK   256    // dk (4 mixtures x 64)
#define LL   2048   // Lq == Lk
#define DV   256    // dv
#define NMIX 4

typedef __attribute__((ext_vector_type(8))) short bf16x8;
typedef __attribute__((ext_vector_type(4))) float f32x4;

__device__ __forceinline__ unsigned short f2bf(float x) {
    unsigned int u = __float_as_uint(x);
    return (unsigned short)((u + 0x7FFFu + ((u >> 16) & 1u)) >> 16);  // RNE
}
__device__ __forceinline__ float bf2f(unsigned short u) {
    return __uint_as_float(((unsigned int)u) << 16);
}

// async global->LDS, 16B per lane; LDS dest is wave-uniform base + lane*16
__device__ __forceinline__ void gl16(const unsigned short* g, unsigned short* l) {
    __builtin_amdgcn_global_load_lds(
        (const __attribute__((address_space(1))) unsigned int*)(const void*)g,
        (__attribute__((address_space(3))) unsigned int*)(void*)l, 16, 0, 0);
}

// ---------------------------------------------------------------------------
// (B, DK, LL) f32 -> (B, LL, DK) bf16-bits (used for Q and K)
__global__ void transpose_cast_k(const float* __restrict__ in,
                                 unsigned short* __restrict__ out) {
    const int b  = blockIdx.z;
    const int ct = blockIdx.y;   // DK/32
    const int lt = blockIdx.x;   // LL/32
    __shared__ float tile[32][33];
    const int tx = threadIdx.x & 31;
    const int ty = threadIdx.x >> 5;   // 0..7
    const float* src = in + ((size_t)b * DK + ct * 32) * LL + lt * 32;
    #pragma unroll
    for (int r = 0; r < 4; ++r)
        tile[ty * 4 + r][tx] = src[(size_t)(ty * 4 + r) * LL + tx];
    __syncthreads();
    unsigned short* dst = out + ((size_t)b * LL + lt * 32) * DK + ct * 32;
    #pragma unroll
    for (int r = 0; r < 4; ++r)
        dst[(size_t)(ty * 4 + r) * DK + tx] = f2bf(tile[tx][ty * 4 + r]);
}

// V (B, DV, LL) f32 -> Vp packed in MFMA B-fragment order:
// Vp[((b*64 + kt)*16 + vj)*512 + lane*8 + j] = V[b][vj*16 + (lane&15)][kt*32 + (lane>>4)*8 + j]
__global__ void vp_build_k(const float* __restrict__ value,
                           unsigned short* __restrict__ Vp) {
    const int gid = blockIdx.x * 256 + threadIdx.x;   // 0..524287
    const int lane = gid & 63;
    const int vj = (gid >> 6) & 15;
    const int kt = (gid >> 10) & 63;
    const int b  = gid >> 16;
    const int lg = lane >> 4, lc = lane & 15;
    const float* src = value + ((size_t)b * DV + vj * 16 + lc) * LL + kt * 32 + lg * 8;
    float4 v0 = *reinterpret_cast<const float4*>(src);
    float4 v1 = *reinterpret_cast<const float4*>(src + 4);
    bf16x8 o;
    o[0] = (short)f2bf(v0.x); o[1] = (short)f2bf(v0.y);
    o[2] = (short)f2bf(v0.z); o[3] = (short)f2bf(v0.w);
    o[4] = (short)f2bf(v1.x); o[5] = (short)f2bf(v1.y);
    o[6] = (short)f2bf(v1.z); o[7] = (short)f2bf(v1.w);
    *reinterpret_cast<bf16x8*>(Vp + (size_t)gid * 8) = o;
}

// avg_query: one block per (b*DK + d) row, mean over LL
__global__ void avg_k(const float* __restrict__ q, float* __restrict__ avg) {
    const int row = blockIdx.x;
    const float* p = q + (size_t)row * LL;
    float s = 0.f;
    for (int i = threadIdx.x; i < LL; i += 256) s += p[i];
    #pragma unroll
    for (int off = 32; off >= 1; off >>= 1) s += __shfl_down(s, off);
    __shared__ float ps[4];
    if ((threadIdx.x & 63) == 0) ps[threadIdx.x >> 6] = s;
    __syncthreads();
    if (threadIdx.x == 0)
        avg[row] = (ps[0] + ps[1] + ps[2] + ps[3]) * (1.0f / LL);
}

// pi = softmax_m( w[m,:] . avg[b,:] ) ; one wave per b
__global__ void pi_k(const float* __restrict__ wgt, const float* __restrict__ avg,
                     float* __restrict__ piOut) {
    const int b = blockIdx.x;
    const int l = threadIdx.x;   // 0..63
    float part[NMIX] = {0.f, 0.f, 0.f, 0.f};
    for (int d = l; d < DK; d += 64) {
        float a = avg[b * DK + d];
        #pragma unroll
        for (int m = 0; m < NMIX; ++m) part[m] += wgt[m * DK + d] * a;
    }
    #pragma unroll
    for (int off = 1; off < 64; off <<= 1) {
        #pragma unroll
        for (int m = 0; m < NMIX; ++m) part[m] += __shfl_xor(part[m], off);
    }
    float mx = fmaxf(fmaxf(part[0], part[1]), fmaxf(part[2], part[3]));
    float e0 = __expf(part[0] - mx), e1 = __expf(part[1] - mx);
    float e2 = __expf(part[2] - mx), e3 = __expf(part[3] - mx);
    float z = e0 + e1 + e2 + e3;
    float mine = (l == 0) ? e0 : (l == 1) ? e1 : (l == 2) ? e2 : e3;
    if (l < NMIX) piOut[b * NMIX + l] = mine / z;
}

// ---------------------------------------------------------------------------
// Kernel A: softmax denominators, k-split in halves.
// Zh[kh][b][q][m] = sum_{k in half} exp(S[m][q][k]/16)
// grid 512 = (b&7) x (qt 0..31, 64 q-rows) x (kHalf 0..1); 4 waves (= q-group).
__launch_bounds__(256, 2)
__global__ void zsum_k(const unsigned short* __restrict__ Qt,
                       const unsigned short* __restrict__ Kt,
                       float* __restrict__ Zh) {
    const int bid = blockIdx.x;
    const int b   = bid & 7;             // XCD affinity
    const int qt  = (bid >> 3) & 31;
    const int kHalf = bid >> 8;
    const int qb  = qt * 64;
    const int tid = threadIdx.x;
    const int w = tid >> 6, lane = tid & 63, lg = lane >> 4, lc = lane & 15;
    const int permlc = ((lc >> 2) << 3) + (lc & 3);

    __shared__ __align__(16) unsigned short Kds[2][32 * 256];   // 2 x 16KB

    // Q B-operand fragments: lane (lg,lc) needs channels m*64 + ch*32 + lg*8..+7
    const unsigned short* qrow = Qt + ((size_t)b * LL + qb + w * 16 + lc) * DK + lg * 8;
    bf16x8 qf[NMIX][2];
    #pragma unroll
    for (int m = 0; m < NMIX; ++m)
        #pragma unroll
        for (int ch = 0; ch < 2; ++ch)
            qf[m][ch] = *reinterpret_cast<const bf16x8*>(qrow + m * 64 + ch * 32);

    // staging: linear LDS dest; inverse-swizzled per-lane global source
    int ksrc[4], ldst[4];
    #pragma unroll
    for (int r = 0; r < 4; ++r) {
        const int o   = (w * 4 + r) * 1024 + lane * 16;   // byte slot in 16KB tile
        const int row = o >> 9;                           // 0..31
        const int cc  = (o >> 4) & 31;
        const int fK  = (row & 3) | (((row >> 3) & 3) << 2);
        ksrc[r] = row * 256 + ((cc ^ fK) << 3);           // shorts
        ldst[r] = (w * 4 + r) * 512;                      // shorts
    }
    const unsigned short* kB = Kt + ((size_t)b * LL + kHalf * 1024) * DK;

    #pragma unroll
    for (int r = 0; r < 4; ++r) gl16(kB + ksrc[r], &Kds[0][ldst[r]]);
    __syncthreads();

    const float ES = 0.09016844005555896f;   // log2(e)/16
    float zs[NMIX] = {0.f, 0.f, 0.f, 0.f};
    for (int t = 0; t < 32; ++t) {
        const int buf = t & 1;
        if (t < 31) {
            const unsigned short* kn = kB + (size_t)(t + 1) * 32 * DK;
            #pragma unroll
            for (int r = 0; r < 4; ++r) gl16(kn + ksrc[r], &Kds[buf ^ 1][ldst[r]]);
        }
        #pragma unroll
        for (int g = 0; g < 2; ++g) {
            const int rbase = (permlc + 4 * g) * 256;
            #pragma unroll
            for (int m = 0; m < NMIX; ++m) {
                bf16x8 a0 = *reinterpret_cast<const bf16x8*>(&Kds[buf][rbase + (((m * 8 + lg) ^ lc) << 3)]);
                bf16x8 a1 = *reinterpret_cast<const bf16x8*>(&Kds[buf][rbase + (((m * 8 + 4 + lg) ^ lc) << 3)]);
                f32x4 s = {0.f, 0.f, 0.f, 0.f};
                s = __builtin_amdgcn_mfma_f32_16x16x32_bf16(a0, qf[m][0], s, 0, 0, 0);
                s = __builtin_amdgcn_mfma_f32_16x16x32_bf16(a1, qf[m][1], s, 0, 0, 0);
                zs[m] += __builtin_amdgcn_exp2f(s[0] * ES) + __builtin_amdgcn_exp2f(s[1] * ES)
                       + __builtin_amdgcn_exp2f(s[2] * ES) + __builtin_amdgcn_exp2f(s[3] * ES);
            }
        }
        __syncthreads();
    }
    #pragma unroll
    for (int m = 0; m < NMIX; ++m) {
        float v = zs[m];
        v += __shfl_xor(v, 16);
        v += __shfl_xor(v, 32);
        zs[m] = v;
    }
    if (lane < 16) {
        float* zp = Zh + (((size_t)kHalf * NB + b) * LL + qb + w * 16 + lane) * NMIX;
        #pragma unroll
        for (int m = 0; m < NMIX; ++m) zp[m] = zs[m];
    }
}

// ---------------------------------------------------------------------------
// Kernel C: attn + O. grid 256 = (b&7) x (qt 0..31, 64 q-rows).
// 8 waves: qg = w>>1 owns 16 q-rows; kh = w&1 processes even/odd 32-k tiles.
// Per 64-k step: one K-stage (32KB dbuf), QK (swapped, per-lane 8 consecutive k),
// combined-softmax E, coalesced attn stores, PV with pre-packed Vp (A=epk!).
// One barrier per step. Final even/odd O-partial reduce through reused LDS.
__launch_bounds__(512, 2)
__global__ void mos_attn(const unsigned short* __restrict__ Qt,
                         const unsigned short* __restrict__ Kt,
                         const unsigned short* __restrict__ Vp,
                         const float* __restrict__ Zh,
                         const float* __restrict__ piAll,
                         float* __restrict__ out,
                         float* __restrict__ attn) {
    const int bid = blockIdx.x;
    const int b   = bid & 7;             // XCD affinity
    const int qt  = bid >> 3;            // 0..31
    const int qb  = qt * 64;
    const int tid = threadIdx.x;
    const int w = tid >> 6, lane = tid & 63, lg = lane >> 4, lc = lane & 15;
    const int qg = w >> 1, kh = w & 1;
    const int permlc = ((lc >> 2) << 3) + (lc & 3);

    __shared__ __align__(16) unsigned short Kds[2][64 * 256];   // 64KB (reused for O-reduce)

    // Q B-operand fragments: lane (lg,lc) needs channels m*64 + ch*32 + lg*8..+7
    const unsigned short* qrow = Qt + ((size_t)b * LL + qb + qg * 16 + lc) * DK + lg * 8;
    bf16x8 qf[NMIX][2];
    #pragma unroll
    for (int m = 0; m < NMIX; ++m)
        #pragma unroll
        for (int ch = 0; ch < 2; ++ch)
            qf[m][ch] = *reinterpret_cast<const bf16x8*>(qrow + m * 64 + ch * 32);

    // per-q scale: pi_m / Z_m
    float scl[NMIX];
    {
        const float* z0 = Zh + ((size_t)b * LL + qb + qg * 16 + lc) * NMIX;
        const float* z1 = Zh + ((size_t)(NB + b) * LL + qb + qg * 16 + lc) * NMIX;
        #pragma unroll
        for (int m = 0; m < NMIX; ++m)
            scl[m] = piAll[b * NMIX + m] / (z0[m] + z1[m]);
    }

    int ksrc[4], ldst[4];
    #pragma unroll
    for (int r = 0; r < 4; ++r) {
        const int o   = (w * 4 + r) * 1024 + lane * 16;   // byte slot in 32KB step
        const int row = o >> 9;                           // 0..63
        const int cc  = (o >> 4) & 31;
        const int fK  = (row & 3) | (((row >> 3) & 3) << 2);
        ksrc[r] = row * 256 + ((cc ^ fK) << 3);
        ldst[r] = (w * 4 + r) * 512;
    }
    const unsigned short* kB = Kt + (size_t)b * LL * DK;

    #pragma unroll
    for (int r = 0; r < 4; ++r) gl16(kB + ksrc[r], &Kds[0][ldst[r]]);
    __syncthreads();

    f32x4 oacc[16];
    #pragma unroll
    for (int vj = 0; vj < 16; ++vj) oacc[vj] = (f32x4){0.f, 0.f, 0.f, 0.f};

    const float ES = 0.09016844005555896f;
    float* arow = attn + ((size_t)b * LL + qb + qg * 16 + lc) * LL + kh * 32 + lg * 8;
    const unsigned short* vpB = Vp + (size_t)b * 64 * 16 * 512;

    for (int j = 0; j < 32; ++j) {
        const int buf = j & 1;
        if (j < 31) {
            const unsigned short* kn = kB + (size_t)(j + 1) * 64 * DK;
            #pragma unroll
            for (int r = 0; r < 4; ++r) gl16(kn + ksrc[r], &Kds[buf ^ 1][ldst[r]]);
        }
        // QK^T (swapped) for tile 2j+kh (rows kh*32.. of this 64-row step)
        float av[8];
        #pragma unroll
        for (int r = 0; r < 8; ++r) av[r] = 0.f;
        #pragma unroll
        for (int g = 0; g < 2; ++g) {
            const int rbase = (kh * 32 + permlc + 4 * g) * 256;
            #pragma unroll
            for (int m = 0; m < NMIX; ++m) {
                bf16x8 a0 = *reinterpret_cast<const bf16x8*>(&Kds[buf][rbase + (((m * 8 + lg) ^ lc) << 3)]);
                bf16x8 a1 = *reinterpret_cast<const bf16x8*>(&Kds[buf][rbase + (((m * 8 + 4 + lg) ^ lc) << 3)]);
                f32x4 s = {0.f, 0.f, 0.f, 0.f};
                s = __builtin_amdgcn_mfma_f32_16x16x32_bf16(a0, qf[m][0], s, 0, 0, 0);
                s = __builtin_amdgcn_mfma_f32_16x16x32_bf16(a1, qf[m][1], s, 0, 0, 0);
                #pragma unroll
                for (int r = 0; r < 4; ++r)
                    av[g * 4 + r] += scl[m] * __builtin_amdgcn_exp2f(s[r] * ES);
            }
        }
        // lane holds combined attn for q=lc(of qg), k = j*64 + kh*32 + lg*8 .. +7
        bf16x8 epk;
        #pragma unroll
        for (int r = 0; r < 8; ++r) epk[r] = (short)f2bf(av[r]);

        f32x4 fa, fb;
        #pragma unroll
        for (int r = 0; r < 4; ++r) {
            fa[r] = bf2f((unsigned short)epk[r]);
            fb[r] = bf2f((unsigned short)epk[r + 4]);
        }
        *reinterpret_cast<f32x4*>(arow + j * 64)     = fa;
        *reinterpret_cast<f32x4*>(arow + j * 64 + 4) = fb;

        // PV: A = epk (M=q, K=32k), B = Vp fragment (contiguous 1KB per load)
        const unsigned short* vpt = vpB + (size_t)(2 * j + kh) * 16 * 512 + lane * 8;
        #pragma unroll
        for (int vj = 0; vj < 16; ++vj) {
            bf16x8 vf = *reinterpret_cast<const bf16x8*>(vpt + vj * 512);
            oacc[vj] = __builtin_amdgcn_mfma_f32_16x16x32_bf16(epk, vf, oacc[vj], 0, 0, 0);
        }
        __syncthreads();
    }

    // combine even/odd k partials: kh=1 -> LDS, kh=0 adds and stores
    float* Ored = reinterpret_cast<float*>(&Kds[0][0]);   // 16384 floats = 64KB
    if (kh == 1) {
        #pragma unroll
        for (int vj = 0; vj < 16; ++vj)
            #pragma unroll
            for (int r = 0; r < 4; ++r)
                Ored[(qg * 16 + lg * 4 + r) * 256 + vj * 16 + lc] = oacc[vj][r];
    }
    __syncthreads();
    if (kh == 0) {
        #pragma unroll
        for (int vj = 0; vj < 16; ++vj) {
            #pragma unroll
            for (int r = 0; r < 4; ++r) {
                float o = oacc[vj][r] + Ored[(qg * 16 + lg * 4 + r) * 256 + vj * 16 + lc];
                out[((size_t)b * LL + qb + qg * 16 + lg * 4 + r) * DV + vj * 16 + lc] = o;
            }
        }
    }
}

// ---------------------------------------------------------------------------
extern "C" void kernel_launch(void* const* d_in, const int* in_sizes, int n_in,
                              void* d_out, int out_size, void* d_ws, size_t ws_size,
                              hipStream_t stream) {
    const float* query   = (const float*)d_in[0];   // (8, 256, 2048)
    const float* key     = (const float*)d_in[1];   // (8, 256, 2048)
    const float* value   = (const float*)d_in[2];   // (8, 256, 2048)
    const float* weights = (const float*)d_in[3];   // (4, 256)

    float* out  = (float*)d_out;                    // (8, 2048, 256)
    float* attn = out + (size_t)NB * LL * DV;       // (8, 2048, 2048)

    // workspace (~25.2 MB)
    char* ws = (char*)d_ws;
    float* avg = (float*)ws;                              // 8KB
    float* pi  = (float*)(ws + 8192);                     // 32B
    float* Zh  = (float*)(ws + 12288);                    // 2*8*2048*4*4B = 512KB
    unsigned short* Qt = (unsigned short*)(ws + 536576);  // (8,2048,256) bf16
    unsigned short* Kt = Qt + (size_t)NB * LL * DK;
    unsigned short* Vp = Kt + (size_t)NB * LL * DK;       // packed V frags

    transpose_cast_k<<<dim3(LL / 32, DK / 32, NB), 256, 0, stream>>>(query, Qt);
    transpose_cast_k<<<dim3(LL / 32, DK / 32, NB), 256, 0, stream>>>(key, Kt);
    vp_build_k<<<2048, 256, 0, stream>>>(value, Vp);
    avg_k<<<NB * DK, 256, 0, stream>>>(query, avg);
    pi_k<<<NB, 64, 0, stream>>>(weights, avg, pi);
    zsum_k<<<512, 256, 0, stream>>>(Qt, Kt, Zh);
    mos_attn<<<256, 512, 0, stream>>>(Qt, Kt, Vp, Zh, pi, out, attn);
}